// Round 4
// baseline (284.360 us; speedup 1.0000x reference)
//
#include <hip/hip_runtime.h>
#include <hip/hip_bf16.h>

#define B_ 8
#define C_ 64
#define OUT_ 64
#define KS_ 16
#define NS_ 4096
#define K_ 32
#define G_ 16   // support points (n) per block

typedef short bf16x8 __attribute__((ext_vector_type(8)));
typedef float f32x4 __attribute__((ext_vector_type(4)));

__device__ inline short f2bf(float f) {
    union { __hip_bfloat16 h; short s; } u;
    u.h = __float2bfloat16(f);
    return u.s;
}

// one-time: weight (1024x64 f32, row-major) -> Wt bf16 [64][1024]
__global__ __launch_bounds__(256) void transpose_w(const float* __restrict__ w,
                                                   short* __restrict__ wt) {
    int idx = blockIdx.x * 256 + threadIdx.x;   // 65536 total
    int j = idx >> 6, o = idx & 63;
    wt[o * 1024 + j] = f2bf(w[idx]);
}

__global__ __launch_bounds__(256, 3) void convpoint_kernel(
    const float* __restrict__ input,      // (B,C,NS,K)
    const float* __restrict__ points,     // (B,3,NS,K)
    const float* __restrict__ support,    // (B,3,NS)
    const short* __restrict__ Wt,         // (OUT,1024) bf16, transposed weight
    const float* __restrict__ bias,       // (OUT)
    const float* __restrict__ centers,    // (3,KS)
    const float* __restrict__ W1, const float* __restrict__ b1,
    const float* __restrict__ W2, const float* __restrict__ b2,
    const float* __restrict__ W3, const float* __restrict__ b3,
    float* __restrict__ out0,             // (B,OUT,NS)
    float* __restrict__ out1)             // (B,3,NS)
{
    // [n][m][k] bf16, byte-swizzle ^((m&7)<<4); row stride 64B
    __shared__ short s_mat[G_ * KS_ * K_];        // 16 KB
    // [n][j] bf16, j=c*16+m, byte-swizzle ^((n&7)<<4); row stride 2048B
    __shared__ short s_F[G_ * 1024];              // 32 KB

    const int tid = threadIdx.x;
    const int bidx = blockIdx.x;
    const int b = bidx / (NS_ / G_);
    const int n0 = (bidx % (NS_ / G_)) * G_;

    const int wave = tid >> 6;
    const int lane = tid & 63;
    const int half = lane >> 5;
    const int kl = lane & 31;

    // ---- output 1: pass-through support_points (independent) ----
    if (tid < 3 * G_) {
        int d = tid >> 4, g = tid & 15;
        int idx = (b * 3 + d) * NS_ + n0 + g;
        out1[idx] = support[idx];
    }

    // ---- Phase A+B: radius normalize + 3-layer MLP -> s_mat[n][m][k] (bf16) ----
    // thread handles (n = 2*wave + half + 8*pi, k = lane&31) for pi=0,1
    #pragma unroll
    for (int pi = 0; pi < 2; ++pi) {
        const int nl = 2 * wave + half + 8 * pi;
        const int n = n0 + nl;
        float p0 = points[((size_t)(b * 3 + 0) * NS_ + n) * K_ + kl] - support[(b * 3 + 0) * NS_ + n];
        float p1 = points[((size_t)(b * 3 + 1) * NS_ + n) * K_ + kl] - support[(b * 3 + 1) * NS_ + n];
        float p2 = points[((size_t)(b * 3 + 2) * NS_ + n) * K_ + kl] - support[(b * 3 + 2) * NS_ + n];
        float r2 = p0 * p0 + p1 * p1 + p2 * p2;
        #pragma unroll
        for (int m2 = 1; m2 < 32; m2 <<= 1)
            r2 = fmaxf(r2, __shfl_xor(r2, m2, 64));
        float maxi = sqrtf(r2);
        float inv = (maxi == 0.f) ? 1.f : 1.f / maxi;

        float rel[48];
        #pragma unroll
        for (int s = 0; s < 16; ++s) {
            rel[s]      = p0 * inv - centers[s];
            rel[16 + s] = p1 * inv - centers[16 + s];
            rel[32 + s] = p2 * inv - centers[32 + s];
        }
        float h1[16];
        #pragma unroll
        for (int i = 0; i < 16; ++i) {
            float a = b1[i];
            #pragma unroll
            for (int j = 0; j < 48; ++j) a += rel[j] * W1[i * 48 + j];
            h1[i] = fmaxf(a, 0.f);
        }
        float h2[16];
        #pragma unroll
        for (int i = 0; i < 16; ++i) {
            float a = b2[i];
            #pragma unroll
            for (int j = 0; j < 16; ++j) a += h1[j] * W2[i * 16 + j];
            h2[i] = fmaxf(a, 0.f);
        }
        #pragma unroll
        for (int i = 0; i < 16; ++i) {
            float a = b3[i];
            #pragma unroll
            for (int j = 0; j < 16; ++j) a += h2[j] * W3[i * 16 + j];
            a = fmaxf(a, 0.f);
            int off = nl * 1024 + i * 64 + kl * 2;          // bytes
            *(short*)((char*)s_mat + (off ^ ((i & 7) << 4))) = f2bf(a);
        }
    }
    __syncthreads();

    // ---- Phase C (MFMA): F[n][c*16+m] = sum_k input[b,c,n,k] * mat[n][k][m] ----
    // wave w: n = 4w..4w+3; per n: B-frag from s_mat, 4 c-tiles of A from global
    {
        const int m15 = lane & 15;
        const int kc = lane >> 4;        // k-chunk: k = kc*8 + e
        #pragma unroll
        for (int i = 0; i < 4; ++i) {
            const int nl = wave * 4 + i;
            const int n = n0 + nl;
            int boff = nl * 1024 + m15 * 64 + kc * 16;       // bytes
            bf16x8 bfrag = *(const bf16x8*)((const char*)s_mat + (boff ^ ((m15 & 7) << 4)));
            #pragma unroll
            for (int ct = 0; ct < 4; ++ct) {
                const int c = ct * 16 + m15;                 // A row
                const float* ap = input + ((size_t)(b * C_ + c) * NS_ + n) * K_ + kc * 8;
                float av[8];
                *(float4*)(av)     = *(const float4*)(ap);
                *(float4*)(av + 4) = *(const float4*)(ap + 4);
                bf16x8 afrag;
                #pragma unroll
                for (int e = 0; e < 8; ++e) afrag[e] = f2bf(av[e]);
                f32x4 acc = {0.f, 0.f, 0.f, 0.f};
                acc = __builtin_amdgcn_mfma_f32_16x16x32_bf16(afrag, bfrag, acc, 0, 0, 0);
                // D: col m = lane&15, row c' = ct*16 + (lane>>4)*4 + r
                #pragma unroll
                for (int r = 0; r < 4; ++r) {
                    int cc = ct * 16 + kc * 4 + r;
                    int j = cc * 16 + m15;
                    int off = nl * 2048 + j * 2;             // bytes
                    *(short*)((char*)s_F + (off ^ ((nl & 7) << 4))) = f2bf(acc[r]);
                }
            }
        }
    }
    __syncthreads();

    // ---- Phase D (MFMA): out[n][o] = (sum_j F[n][j] * Wt[o][j])/32 + bias[o] ----
    // GEMM M=16(n) N=16(o per wave, otile=wave) K=1024
    {
        const int m15 = lane & 15;
        const int kc = lane >> 4;
        const int o = wave * 16 + m15;
        f32x4 acc0 = {0.f, 0.f, 0.f, 0.f};
        f32x4 acc1 = {0.f, 0.f, 0.f, 0.f};
        const short* wrow = Wt + o * 1024;
        #pragma unroll
        for (int ks = 0; ks < 32; ++ks) {
            const int j0 = kc * 8 + ks * 32;
            int aoff = m15 * 2048 + j0 * 2;                  // bytes; n = m15
            bf16x8 af = *(const bf16x8*)((const char*)s_F + (aoff ^ ((m15 & 7) << 4)));
            bf16x8 bf = *(const bf16x8*)(wrow + j0);
            if (ks & 1) acc1 = __builtin_amdgcn_mfma_f32_16x16x32_bf16(af, bf, acc1, 0, 0, 0);
            else        acc0 = __builtin_amdgcn_mfma_f32_16x16x32_bf16(af, bf, acc0, 0, 0, 0);
        }
        const float bo = bias[o];
        float4 ov;
        ov.x = (acc0[0] + acc1[0]) * (1.f / 32.f) + bo;
        ov.y = (acc0[1] + acc1[1]) * (1.f / 32.f) + bo;
        ov.z = (acc0[2] + acc1[2]) * (1.f / 32.f) + bo;
        ov.w = (acc0[3] + acc1[3]) * (1.f / 32.f) + bo;
        // D rows: n = kc*4 + r (4 consecutive) at col o
        *(float4*)&out0[(size_t)(b * OUT_ + o) * NS_ + n0 + kc * 4] = ov;
    }
}

extern "C" void kernel_launch(void* const* d_in, const int* in_sizes, int n_in,
                              void* d_out, int out_size, void* d_ws, size_t ws_size,
                              hipStream_t stream) {
    const float* input   = (const float*)d_in[0];
    const float* points  = (const float*)d_in[1];
    const float* support = (const float*)d_in[2];
    const float* weight  = (const float*)d_in[3];
    const float* bias    = (const float*)d_in[4];
    const float* centers = (const float*)d_in[5];
    const float* W1 = (const float*)d_in[6];
    const float* b1 = (const float*)d_in[7];
    const float* W2 = (const float*)d_in[8];
    const float* b2 = (const float*)d_in[9];
    const float* W3 = (const float*)d_in[10];
    const float* b3 = (const float*)d_in[11];

    float* out0 = (float*)d_out;
    float* out1 = out0 + (size_t)B_ * OUT_ * NS_;

    short* wt = (short*)d_ws;   // 64*1024*2 = 128 KB scratch
    transpose_w<<<256, 256, 0, stream>>>(weight, wt);

    dim3 grid(B_ * (NS_ / G_));
    convpoint_kernel<<<grid, 256, 0, stream>>>(
        input, points, support, wt, bias, centers,
        W1, b1, W2, b2, W3, b3, out0, out1);
}

// Round 5
// 154.798 us; speedup vs baseline: 1.8370x; 1.8370x over previous
//
#include <hip/hip_runtime.h>
#include <hip/hip_bf16.h>

#define B_ 8
#define C_ 64
#define OUT_ 64
#define KS_ 16
#define NS_ 4096
#define K_ 32
#define G_ 16   // support points (n) per block

typedef short bf16x8 __attribute__((ext_vector_type(8)));
typedef float f32x4 __attribute__((ext_vector_type(4)));

__device__ inline short f2bf(float f) {
    union { __hip_bfloat16 h; short s; } u;
    u.h = __float2bfloat16(f);
    return u.s;
}

// one-time: weight (1024x64 f32, row-major) -> Wt bf16 [64][1024]
__global__ __launch_bounds__(256) void transpose_w(const float* __restrict__ w,
                                                   short* __restrict__ wt) {
    int idx = blockIdx.x * 256 + threadIdx.x;   // 65536 total
    int j = idx >> 6, o = idx & 63;
    wt[o * 1024 + j] = f2bf(w[idx]);
}

__global__ __launch_bounds__(256) void convpoint_kernel(
    const float* __restrict__ input,      // (B,C,NS,K)
    const float* __restrict__ points,     // (B,3,NS,K)
    const float* __restrict__ support,    // (B,3,NS)
    const short* __restrict__ Wt,         // (OUT,1024) bf16, transposed weight
    const float* __restrict__ bias,       // (OUT)
    const float* __restrict__ centers,    // (3,KS)
    const float* __restrict__ W1, const float* __restrict__ b1,
    const float* __restrict__ W2, const float* __restrict__ b2,
    const float* __restrict__ W3, const float* __restrict__ b3,
    float* __restrict__ out0,             // (B,OUT,NS)
    float* __restrict__ out1)             // (B,3,NS)
{
    // [n][m][k] bf16, byte-swizzle ^((m&7)<<4); row stride 64B
    __shared__ short s_mat[G_ * KS_ * K_];        // 16 KB
    // [n][j] bf16, j=c*16+m, byte-swizzle ^((n&7)<<4); row stride 2048B
    // NOTE: first 5.5 KB aliased as f32 staging for MLP params during phase A/B
    __shared__ short s_F[G_ * 1024];              // 32 KB

    float* stg = (float*)s_F;
    // staging layout (floats): [0,768) W1 | [768,1024) W2 | [1024,1280) W3
    //                          [1280,1296) b1 | [1296,1312) b2 | [1312,1328) b3 | [1328,1376) centers
    const float* sW1 = stg;
    const float* sW2 = stg + 768;
    const float* sW3 = stg + 1024;
    const float* sb1 = stg + 1280;
    const float* sb2 = stg + 1296;
    const float* sb3 = stg + 1312;
    const float* scent = stg + 1328;

    const int tid = threadIdx.x;
    const int bidx = blockIdx.x;
    const int b = bidx / (NS_ / G_);
    const int n0 = (bidx % (NS_ / G_)) * G_;

    const int wave = tid >> 6;
    const int lane = tid & 63;
    const int half = lane >> 5;
    const int kl = lane & 31;

    // ---- stage MLP params into LDS (aliased on s_F; dead after phase B sync) ----
    for (int i = tid; i < 768; i += 256) stg[i] = W1[i];
    {
        stg[768 + tid] = W2[tid];
        stg[1024 + tid] = W3[tid];
    }
    if (tid < 16) {
        stg[1280 + tid] = b1[tid];
        stg[1296 + tid] = b2[tid];
        stg[1312 + tid] = b3[tid];
    }
    if (tid < 48) stg[1328 + tid] = centers[tid];

    // ---- output 1: pass-through support_points (independent) ----
    if (tid < 3 * G_) {
        int d = tid >> 4, g = tid & 15;
        int idx = (b * 3 + d) * NS_ + n0 + g;
        out1[idx] = support[idx];
    }
    __syncthreads();

    // ---- Phase A+B: radius normalize + 3-layer MLP -> s_mat[n][m][k] (bf16) ----
    // thread handles (n = 2*wave + half + 8*pi, k = lane&31) for pi=0,1
    #pragma unroll
    for (int pi = 0; pi < 2; ++pi) {
        const int nl = 2 * wave + half + 8 * pi;
        const int n = n0 + nl;
        float p0 = points[((size_t)(b * 3 + 0) * NS_ + n) * K_ + kl] - support[(b * 3 + 0) * NS_ + n];
        float p1 = points[((size_t)(b * 3 + 1) * NS_ + n) * K_ + kl] - support[(b * 3 + 1) * NS_ + n];
        float p2 = points[((size_t)(b * 3 + 2) * NS_ + n) * K_ + kl] - support[(b * 3 + 2) * NS_ + n];
        float r2 = p0 * p0 + p1 * p1 + p2 * p2;
        #pragma unroll
        for (int m2 = 1; m2 < 32; m2 <<= 1)
            r2 = fmaxf(r2, __shfl_xor(r2, m2, 64));
        float maxi = sqrtf(r2);
        float inv = (maxi == 0.f) ? 1.f : 1.f / maxi;

        float rel[48];
        #pragma unroll
        for (int s = 0; s < 16; ++s) {
            rel[s]      = p0 * inv - scent[s];
            rel[16 + s] = p1 * inv - scent[16 + s];
            rel[32 + s] = p2 * inv - scent[32 + s];
        }
        float h1[16];
        #pragma unroll
        for (int i = 0; i < 16; ++i) {
            float a = sb1[i];
            #pragma unroll
            for (int j = 0; j < 48; ++j) a += rel[j] * sW1[i * 48 + j];
            h1[i] = fmaxf(a, 0.f);
        }
        float h2[16];
        #pragma unroll
        for (int i = 0; i < 16; ++i) {
            float a = sb2[i];
            #pragma unroll
            for (int j = 0; j < 16; ++j) a += h1[j] * sW2[i * 16 + j];
            h2[i] = fmaxf(a, 0.f);
        }
        #pragma unroll
        for (int i = 0; i < 16; ++i) {
            float a = sb3[i];
            #pragma unroll
            for (int j = 0; j < 16; ++j) a += h2[j] * sW3[i * 16 + j];
            a = fmaxf(a, 0.f);
            int off = nl * 1024 + i * 64 + kl * 2;          // bytes
            *(short*)((char*)s_mat + (off ^ ((i & 7) << 4))) = f2bf(a);
        }
    }
    __syncthreads();

    // ---- Phase C (MFMA): F[n][c*16+m] = sum_k input[b,c,n,k] * mat[n][k][m] ----
    // wave w: n = 4w..4w+3; per n: B-frag from s_mat, 4 c-tiles of A from global
    {
        const int m15 = lane & 15;
        const int kc = lane >> 4;        // k-chunk: k = kc*8 + e
        #pragma unroll
        for (int i = 0; i < 4; ++i) {
            const int nl = wave * 4 + i;
            const int n = n0 + nl;
            int boff = nl * 1024 + m15 * 64 + kc * 16;       // bytes
            bf16x8 bfrag = *(const bf16x8*)((const char*)s_mat + (boff ^ ((m15 & 7) << 4)));
            #pragma unroll
            for (int ct = 0; ct < 4; ++ct) {
                const int c = ct * 16 + m15;                 // A row
                const float* ap = input + ((size_t)(b * C_ + c) * NS_ + n) * K_ + kc * 8;
                float av[8];
                *(float4*)(av)     = *(const float4*)(ap);
                *(float4*)(av + 4) = *(const float4*)(ap + 4);
                bf16x8 afrag;
                #pragma unroll
                for (int e = 0; e < 8; ++e) afrag[e] = f2bf(av[e]);
                f32x4 acc = {0.f, 0.f, 0.f, 0.f};
                acc = __builtin_amdgcn_mfma_f32_16x16x32_bf16(afrag, bfrag, acc, 0, 0, 0);
                // D: col m = lane&15, row c' = ct*16 + (lane>>4)*4 + r
                #pragma unroll
                for (int r = 0; r < 4; ++r) {
                    int cc = ct * 16 + kc * 4 + r;
                    int j = cc * 16 + m15;
                    int off = nl * 2048 + j * 2;             // bytes
                    *(short*)((char*)s_F + (off ^ ((nl & 7) << 4))) = f2bf(acc[r]);
                }
            }
        }
    }
    __syncthreads();

    // ---- Phase D (MFMA): out[n][o] = (sum_j F[n][j] * Wt[o][j])/32 + bias[o] ----
    // GEMM M=16(n) N=16(o per wave, otile=wave) K=1024
    {
        const int m15 = lane & 15;
        const int kc = lane >> 4;
        const int o = wave * 16 + m15;
        f32x4 acc0 = {0.f, 0.f, 0.f, 0.f};
        f32x4 acc1 = {0.f, 0.f, 0.f, 0.f};
        const short* wrow = Wt + o * 1024;
        #pragma unroll
        for (int ks = 0; ks < 32; ++ks) {
            const int j0 = kc * 8 + ks * 32;
            int aoff = m15 * 2048 + j0 * 2;                  // bytes; n = m15
            bf16x8 af = *(const bf16x8*)((const char*)s_F + (aoff ^ ((m15 & 7) << 4)));
            bf16x8 bf = *(const bf16x8*)(wrow + j0);
            if (ks & 1) acc1 = __builtin_amdgcn_mfma_f32_16x16x32_bf16(af, bf, acc1, 0, 0, 0);
            else        acc0 = __builtin_amdgcn_mfma_f32_16x16x32_bf16(af, bf, acc0, 0, 0, 0);
        }
        const float bo = bias[o];
        float4 ov;
        ov.x = (acc0[0] + acc1[0]) * (1.f / 32.f) + bo;
        ov.y = (acc0[1] + acc1[1]) * (1.f / 32.f) + bo;
        ov.z = (acc0[2] + acc1[2]) * (1.f / 32.f) + bo;
        ov.w = (acc0[3] + acc1[3]) * (1.f / 32.f) + bo;
        // D rows: n = kc*4 + r (4 consecutive) at col o
        *(float4*)&out0[(size_t)(b * OUT_ + o) * NS_ + n0 + kc * 4] = ov;
    }
}

extern "C" void kernel_launch(void* const* d_in, const int* in_sizes, int n_in,
                              void* d_out, int out_size, void* d_ws, size_t ws_size,
                              hipStream_t stream) {
    const float* input   = (const float*)d_in[0];
    const float* points  = (const float*)d_in[1];
    const float* support = (const float*)d_in[2];
    const float* weight  = (const float*)d_in[3];
    const float* bias    = (const float*)d_in[4];
    const float* centers = (const float*)d_in[5];
    const float* W1 = (const float*)d_in[6];
    const float* b1 = (const float*)d_in[7];
    const float* W2 = (const float*)d_in[8];
    const float* b2 = (const float*)d_in[9];
    const float* W3 = (const float*)d_in[10];
    const float* b3 = (const float*)d_in[11];

    float* out0 = (float*)d_out;
    float* out1 = out0 + (size_t)B_ * OUT_ * NS_;

    short* wt = (short*)d_ws;   // 64*1024*2 = 128 KB scratch
    transpose_w<<<256, 256, 0, stream>>>(weight, wt);

    dim3 grid(B_ * (NS_ / G_));
    convpoint_kernel<<<grid, 256, 0, stream>>>(
        input, points, support, wt, bias, centers,
        W1, b1, W2, b2, W3, b3, out0, out1);
}

// Round 6
// 96.475 us; speedup vs baseline: 2.9475x; 1.6045x over previous
//
#include <hip/hip_runtime.h>
#include <hip/hip_bf16.h>

#define B_ 8
#define C_ 64
#define OUT_ 64
#define KS_ 16
#define NS_ 4096
#define K_ 32
#define G_ 16   // support points (n) per block

typedef short bf16x8 __attribute__((ext_vector_type(8)));
typedef float f32x4 __attribute__((ext_vector_type(4)));

__device__ inline short f2bf(float f) {
    union { __hip_bfloat16 h; short s; } u;
    u.h = __float2bfloat16(f);
    return u.s;
}

// s_F swizzle: row bits (>>11) spread reads; kc bits (>>7) spread writes.
// Pure function of byte offset -> write/read consistency guaranteed.
__device__ inline int swzF(int byte) {
    return byte ^ ((((byte >> 11) & 7) << 4) | (((byte >> 7) & 3) << 5));
}

// one-time: weight (1024x64 f32, row-major) -> Wt bf16 [64][1024]
__global__ __launch_bounds__(256) void transpose_w(const float* __restrict__ w,
                                                   short* __restrict__ wt) {
    int idx = blockIdx.x * 256 + threadIdx.x;   // 65536 total
    int j = idx >> 6, o = idx & 63;
    wt[o * 1024 + j] = f2bf(w[idx]);
}

// one-time: collapse layer 1.  W1c[i] = {sum_s W1[i][0*16+s], sum_s W1[i][1*16+s],
//                                        sum_s W1[i][2*16+s], b1[i]-sum_j W1[i][j]*cent[j]}
__global__ void prep_w1(const float* __restrict__ W1, const float* __restrict__ b1,
                        const float* __restrict__ centers, float* __restrict__ w1c) {
    int i = threadIdx.x;
    if (i < 16) {
        float s0 = 0.f, s1 = 0.f, s2 = 0.f, c = b1[i];
        for (int s = 0; s < 16; ++s) {
            s0 += W1[i * 48 + s];
            s1 += W1[i * 48 + 16 + s];
            s2 += W1[i * 48 + 32 + s];
        }
        for (int j = 0; j < 48; ++j) c -= W1[i * 48 + j] * centers[j];
        ((float4*)w1c)[i] = make_float4(s0, s1, s2, c);
    }
}

__global__ __launch_bounds__(256) void convpoint_kernel(
    const float* __restrict__ input,      // (B,C,NS,K)
    const float* __restrict__ points,     // (B,3,NS,K)
    const float* __restrict__ support,    // (B,3,NS)
    const short* __restrict__ Wt,         // (OUT,1024) bf16, transposed weight
    const float* __restrict__ W1c,        // (16,4) collapsed layer-1
    const float* __restrict__ bias,       // (OUT)
    const float* __restrict__ W2, const float* __restrict__ b2,
    const float* __restrict__ W3, const float* __restrict__ b3,
    float* __restrict__ out0,             // (B,OUT,NS)
    float* __restrict__ out1)             // (B,3,NS)
{
    // [n][m][k] bf16, byte-swizzle ^((m&7)<<4); row stride 64B
    __shared__ short s_mat[G_ * KS_ * K_];        // 16 KB
    // [n][j] bf16, j=c*16+m, swizzle swzF; row stride 2048B
    // first 2.4 KB aliased as f32 staging for MLP params during phase A/B
    __shared__ short s_F[G_ * 1024];              // 32 KB

    float* stg = (float*)s_F;
    // staging (floats): [0,256) W2 | [256,512) W3 | [512,576) W1c | [576,592) b2 | [592,608) b3
    const float* sW2 = stg;
    const float* sW3 = stg + 256;
    const float4* sW1c = (const float4*)(stg + 512);
    const float* sb2 = stg + 576;
    const float* sb3 = stg + 592;

    const int tid = threadIdx.x;
    const int bidx = blockIdx.x;
    const int b = bidx / (NS_ / G_);
    const int n0 = (bidx % (NS_ / G_)) * G_;

    const int wave = tid >> 6;
    const int lane = tid & 63;
    const int half = lane >> 5;
    const int kl = lane & 31;

    // ---- stage MLP params into LDS (aliased on s_F; dead after phase B sync) ----
    if (tid < 256) { stg[tid] = W2[tid]; stg[256 + tid] = W3[tid]; }
    if (tid < 64) stg[512 + tid] = W1c[tid];
    if (tid < 16) { stg[576 + tid] = b2[tid]; stg[592 + tid] = b3[tid]; }

    // ---- output 1: pass-through support_points (independent) ----
    if (tid < 3 * G_) {
        int d = tid >> 4, g = tid & 15;
        int idx = (b * 3 + d) * NS_ + n0 + g;
        out1[idx] = support[idx];
    }
    __syncthreads();

    // ---- Phase A+B: normalize + collapsed 3-layer MLP (2 points interleaved) ----
    // thread handles (n = 2*wave + half + 8*pi, k = lane&31) for pi=0,1
    {
        const int nla = 2 * wave + half;       // pi=0
        const int nlb = nla + 8;               // pi=1
        float pa[3], pb[3];
        float r2a = 0.f, r2b = 0.f;
        #pragma unroll
        for (int d = 0; d < 3; ++d) {
            const float* pp = points + ((size_t)(b * 3 + d) * NS_ + n0) * K_;
            const float* sp = support + (b * 3 + d) * NS_ + n0;
            pa[d] = pp[nla * K_ + kl] - sp[nla];
            pb[d] = pp[nlb * K_ + kl] - sp[nlb];
            r2a += pa[d] * pa[d];
            r2b += pb[d] * pb[d];
        }
        #pragma unroll
        for (int m2 = 1; m2 < 32; m2 <<= 1) {
            r2a = fmaxf(r2a, __shfl_xor(r2a, m2, 64));
            r2b = fmaxf(r2b, __shfl_xor(r2b, m2, 64));
        }
        float ma = sqrtf(r2a), mb = sqrtf(r2b);
        float iva = (ma == 0.f) ? 1.f : 1.f / ma;
        float ivb = (mb == 0.f) ? 1.f : 1.f / mb;
        #pragma unroll
        for (int d = 0; d < 3; ++d) { pa[d] *= iva; pb[d] *= ivb; }

        float h1a[16], h1b[16];
        #pragma unroll
        for (int i = 0; i < 16; ++i) {
            float4 w = sW1c[i];
            h1a[i] = fmaxf(w.x * pa[0] + w.y * pa[1] + w.z * pa[2] + w.w, 0.f);
            h1b[i] = fmaxf(w.x * pb[0] + w.y * pb[1] + w.z * pb[2] + w.w, 0.f);
        }
        float h2a[16], h2b[16];
        #pragma unroll
        for (int i = 0; i < 16; ++i) {
            float fa = sb2[i], fb = fa;
            #pragma unroll
            for (int j = 0; j < 16; ++j) {
                float w = sW2[i * 16 + j];
                fa += h1a[j] * w;
                fb += h1b[j] * w;
            }
            h2a[i] = fmaxf(fa, 0.f);
            h2b[i] = fmaxf(fb, 0.f);
        }
        #pragma unroll
        for (int i = 0; i < 16; ++i) {
            float fa = sb3[i], fb = fa;
            #pragma unroll
            for (int j = 0; j < 16; ++j) {
                float w = sW3[i * 16 + j];
                fa += h2a[j] * w;
                fb += h2b[j] * w;
            }
            fa = fmaxf(fa, 0.f);
            fb = fmaxf(fb, 0.f);
            int offa = nla * 1024 + i * 64 + kl * 2;        // bytes
            int offb = nlb * 1024 + i * 64 + kl * 2;
            *(short*)((char*)s_mat + (offa ^ ((i & 7) << 4))) = f2bf(fa);
            *(short*)((char*)s_mat + (offb ^ ((i & 7) << 4))) = f2bf(fb);
        }
    }
    __syncthreads();

    // ---- Phase C (MFMA): F[n][c*16+m] = sum_k input[b,c,n,k] * mat[n][k][m] ----
    // wave w: n = 4w..4w+3; per n: B-frag from s_mat, 4 c-tiles of A from global
    {
        const int m15 = lane & 15;
        const int kc = lane >> 4;        // k-chunk: k = kc*8 + e
        #pragma unroll
        for (int i = 0; i < 4; ++i) {
            const int nl = wave * 4 + i;
            const int n = n0 + nl;
            int boff = nl * 1024 + m15 * 64 + kc * 16;       // bytes
            bf16x8 bfrag = *(const bf16x8*)((const char*)s_mat + (boff ^ ((m15 & 7) << 4)));
            #pragma unroll
            for (int ct = 0; ct < 4; ++ct) {
                const int c = ct * 16 + m15;                 // A row
                const float* ap = input + ((size_t)(b * C_ + c) * NS_ + n) * K_ + kc * 8;
                float av[8];
                *(float4*)(av)     = *(const float4*)(ap);
                *(float4*)(av + 4) = *(const float4*)(ap + 4);
                bf16x8 afrag;
                #pragma unroll
                for (int e = 0; e < 8; ++e) afrag[e] = f2bf(av[e]);
                f32x4 acc = {0.f, 0.f, 0.f, 0.f};
                acc = __builtin_amdgcn_mfma_f32_16x16x32_bf16(afrag, bfrag, acc, 0, 0, 0);
                // D: col m = lane&15, row c' = ct*16 + (lane>>4)*4 + r
                #pragma unroll
                for (int r = 0; r < 4; ++r) {
                    int cc = ct * 16 + kc * 4 + r;
                    int j = cc * 16 + m15;
                    int off = nl * 2048 + j * 2;             // bytes
                    *(short*)((char*)s_F + swzF(off)) = f2bf(acc[r]);
                }
            }
        }
    }
    __syncthreads();

    // ---- Phase D (MFMA): out[n][o] = (sum_j F[n][j] * Wt[o][j])/32 + bias[o] ----
    // GEMM M=16(n) N=16(o per wave, otile=wave) K=1024
    {
        const int m15 = lane & 15;
        const int kc = lane >> 4;
        const int o = wave * 16 + m15;
        f32x4 acc0 = {0.f, 0.f, 0.f, 0.f};
        f32x4 acc1 = {0.f, 0.f, 0.f, 0.f};
        const short* wrow = Wt + o * 1024;
        #pragma unroll
        for (int ks = 0; ks < 32; ++ks) {
            const int j0 = kc * 8 + ks * 32;
            int aoff = m15 * 2048 + j0 * 2;                  // bytes; n = m15
            bf16x8 af = *(const bf16x8*)((const char*)s_F + swzF(aoff));
            bf16x8 bf = *(const bf16x8*)(wrow + j0);
            if (ks & 1) acc1 = __builtin_amdgcn_mfma_f32_16x16x32_bf16(af, bf, acc1, 0, 0, 0);
            else        acc0 = __builtin_amdgcn_mfma_f32_16x16x32_bf16(af, bf, acc0, 0, 0, 0);
        }
        const float bo = bias[o];
        float4 ov;
        ov.x = (acc0[0] + acc1[0]) * (1.f / 32.f) + bo;
        ov.y = (acc0[1] + acc1[1]) * (1.f / 32.f) + bo;
        ov.z = (acc0[2] + acc1[2]) * (1.f / 32.f) + bo;
        ov.w = (acc0[3] + acc1[3]) * (1.f / 32.f) + bo;
        // D rows: n = kc*4 + r (4 consecutive) at col o
        *(float4*)&out0[(size_t)(b * OUT_ + o) * NS_ + n0 + kc * 4] = ov;
    }
}

extern "C" void kernel_launch(void* const* d_in, const int* in_sizes, int n_in,
                              void* d_out, int out_size, void* d_ws, size_t ws_size,
                              hipStream_t stream) {
    const float* input   = (const float*)d_in[0];
    const float* points  = (const float*)d_in[1];
    const float* support = (const float*)d_in[2];
    const float* weight  = (const float*)d_in[3];
    const float* bias    = (const float*)d_in[4];
    const float* centers = (const float*)d_in[5];
    const float* W1 = (const float*)d_in[6];
    const float* b1 = (const float*)d_in[7];
    const float* W2 = (const float*)d_in[8];
    const float* b2 = (const float*)d_in[9];
    const float* W3 = (const float*)d_in[10];
    const float* b3 = (const float*)d_in[11];

    float* out0 = (float*)d_out;
    float* out1 = out0 + (size_t)B_ * OUT_ * NS_;

    short* wt  = (short*)d_ws;                       // 128 KB
    float* w1c = (float*)((char*)d_ws + 131072);     // 256 B
    transpose_w<<<256, 256, 0, stream>>>(weight, wt);
    prep_w1<<<1, 64, 0, stream>>>(W1, b1, centers, w1c);

    dim3 grid(B_ * (NS_ / G_));
    convpoint_kernel<<<grid, 256, 0, stream>>>(
        input, points, support, wt, w1c, bias,
        W2, b2, W3, b3, out0, out1);
}

// Round 8
// 92.601 us; speedup vs baseline: 3.0708x; 1.0418x over previous
//
#include <hip/hip_runtime.h>
#include <hip/hip_bf16.h>

#define B_ 8
#define C_ 64
#define OUT_ 64
#define KS_ 16
#define NS_ 4096
#define K_ 32
#define G_ 16   // support points (n) per block

typedef short bf16x8 __attribute__((ext_vector_type(8)));
typedef float f32x4 __attribute__((ext_vector_type(4)));
typedef float f32x2 __attribute__((ext_vector_type(2)));

__device__ inline short f2bf(float f) {
    union { __hip_bfloat16 h; short s; } u;
    u.h = __float2bfloat16(f);
    return u.s;
}

__device__ inline f32x2 relu2(f32x2 v) {
    v.x = fmaxf(v.x, 0.f);
    v.y = fmaxf(v.y, 0.f);
    return v;
}

// s_F swizzle: row bits (>>11) spread reads; kc bits (>>7) spread writes.
__device__ inline int swzF(int byte) {
    return byte ^ ((((byte >> 11) & 7) << 4) | (((byte >> 7) & 3) << 5));
}

// one-time setup: blocks 0-255 transpose weight -> Wt bf16 [64][1024];
// block 256 collapses layer 1.
__global__ __launch_bounds__(256) void setup_kernel(
    const float* __restrict__ w, short* __restrict__ wt,
    const float* __restrict__ W1, const float* __restrict__ b1,
    const float* __restrict__ centers, float* __restrict__ w1c) {
    int bid = blockIdx.x;
    if (bid < 256) {
        int idx = bid * 256 + threadIdx.x;   // 65536 total
        int j = idx >> 6, o = idx & 63;
        wt[o * 1024 + j] = f2bf(w[idx]);
    } else {
        int i = threadIdx.x;
        if (i < 16) {
            float s0 = 0.f, s1 = 0.f, s2 = 0.f, c = b1[i];
            for (int s = 0; s < 16; ++s) {
                s0 += W1[i * 48 + s];
                s1 += W1[i * 48 + 16 + s];
                s2 += W1[i * 48 + 32 + s];
            }
            for (int j = 0; j < 48; ++j) c -= W1[i * 48 + j] * centers[j];
            ((float4*)w1c)[i] = make_float4(s0, s1, s2, c);
        }
    }
}

__global__ __launch_bounds__(256) void convpoint_kernel(
    const float* __restrict__ input,      // (B,C,NS,K)
    const float* __restrict__ points,     // (B,3,NS,K)
    const float* __restrict__ support,    // (B,3,NS)
    const short* __restrict__ Wt,         // (OUT,1024) bf16, transposed weight
    const float* __restrict__ W1c,        // (16,4) collapsed layer-1
    const float* __restrict__ bias,       // (OUT)
    const float* __restrict__ W2, const float* __restrict__ b2,
    const float* __restrict__ W3, const float* __restrict__ b3,
    float* __restrict__ out0,             // (B,OUT,NS)
    float* __restrict__ out1)             // (B,3,NS)
{
    // [n][m][k] bf16, byte-swizzle ^((m&7)<<4); row stride 64B
    __shared__ short s_mat[G_ * KS_ * K_];        // 16 KB
    // [n][j] bf16, j=c*16+m, swizzle swzF; row stride 2048B
    __shared__ short s_F[G_ * 1024];              // 32 KB

    const int tid = threadIdx.x;
    const int bidx = blockIdx.x;
    const int b = bidx / (NS_ / G_);
    const int n0 = (bidx % (NS_ / G_)) * G_;

    const int wave = tid >> 6;
    const int lane = tid & 63;
    const int half = lane >> 5;
    const int kl = lane & 31;

    // ---- output 1: pass-through support_points (independent) ----
    if (tid < 3 * G_) {
        int d = tid >> 4, g = tid & 15;
        int idx = (b * 3 + d) * NS_ + n0 + g;
        out1[idx] = support[idx];
    }

    // ---- Phase A+B: normalize + collapsed 3-layer MLP, 2 points packed f32x2 ----
    // weights via wave-uniform global reads -> SGPR s_loads (scalar cache)
    {
        const int nla = 2 * wave + half;       // local n for point a
        const int nlb = nla + 8;               // local n for point b
        const int na = n0 + nla, nb = n0 + nlb;
        f32x2 p[3];
        f32x2 r2 = {0.f, 0.f};
        #pragma unroll
        for (int d = 0; d < 3; ++d) {
            const float* pp = points + (size_t)(b * 3 + d) * NS_ * K_;
            const float* sp = support + (b * 3 + d) * NS_;
            p[d].x = pp[(size_t)na * K_ + kl] - sp[na];
            p[d].y = pp[(size_t)nb * K_ + kl] - sp[nb];
            r2 += p[d] * p[d];
        }
        float r2a = r2.x, r2b = r2.y;
        #pragma unroll
        for (int m2 = 1; m2 < 32; m2 <<= 1) {
            r2a = fmaxf(r2a, __shfl_xor(r2a, m2, 64));
            r2b = fmaxf(r2b, __shfl_xor(r2b, m2, 64));
        }
        float ma = sqrtf(r2a), mb = sqrtf(r2b);
        f32x2 inv;
        inv.x = (ma == 0.f) ? 1.f : 1.f / ma;
        inv.y = (mb == 0.f) ? 1.f : 1.f / mb;
        #pragma unroll
        for (int d = 0; d < 3; ++d) p[d] *= inv;

        f32x2 h1[16];
        #pragma unroll
        for (int i = 0; i < 16; ++i) {
            float4 w = ((const float4*)W1c)[i];          // uniform -> SGPR
            f32x2 a = p[0] * w.x + p[1] * w.y + p[2] * w.z + w.w;
            h1[i] = relu2(a);
        }
        f32x2 h2[16];
        #pragma unroll
        for (int i = 0; i < 16; ++i) {
            f32x2 a = b2[i];
            #pragma unroll
            for (int j = 0; j < 16; ++j)
                a += h1[j] * W2[i * 16 + j];             // uniform -> SGPR, v_pk_fma
            h2[i] = relu2(a);
        }
        #pragma unroll
        for (int i = 0; i < 16; ++i) {
            f32x2 a = b3[i];
            #pragma unroll
            for (int j = 0; j < 16; ++j)
                a += h2[j] * W3[i * 16 + j];
            a = relu2(a);
            int offa = nla * 1024 + i * 64 + kl * 2;     // bytes
            int offb = nlb * 1024 + i * 64 + kl * 2;
            *(short*)((char*)s_mat + (offa ^ ((i & 7) << 4))) = f2bf(a.x);
            *(short*)((char*)s_mat + (offb ^ ((i & 7) << 4))) = f2bf(a.y);
        }
    }
    __syncthreads();

    // ---- Phase C (MFMA): F[n][c*16+m] = sum_k input[b,c,n,k] * mat[n][k][m] ----
    // wave w: n = 4w..4w+3; per n: B-frag from s_mat, 4 c-tiles of A from global
    {
        const int m15 = lane & 15;
        const int kc = lane >> 4;        // k-chunk: k = kc*8 + e
        #pragma unroll
        for (int i = 0; i < 4; ++i) {
            const int nl = wave * 4 + i;
            const int n = n0 + nl;
            int boff = nl * 1024 + m15 * 64 + kc * 16;       // bytes
            bf16x8 bfrag = *(const bf16x8*)((const char*)s_mat + (boff ^ ((m15 & 7) << 4)));
            #pragma unroll
            for (int ct = 0; ct < 4; ++ct) {
                const int c = ct * 16 + m15;                 // A row
                const float* ap = input + ((size_t)(b * C_ + c) * NS_ + n) * K_ + kc * 8;
                float av[8];
                *(float4*)(av)     = *(const float4*)(ap);
                *(float4*)(av + 4) = *(const float4*)(ap + 4);
                bf16x8 afrag;
                #pragma unroll
                for (int e = 0; e < 8; ++e) afrag[e] = f2bf(av[e]);
                f32x4 acc = {0.f, 0.f, 0.f, 0.f};
                acc = __builtin_amdgcn_mfma_f32_16x16x32_bf16(afrag, bfrag, acc, 0, 0, 0);
                // D: col m = lane&15, row c' = ct*16 + (lane>>4)*4 + r
                #pragma unroll
                for (int r = 0; r < 4; ++r) {
                    int cc = ct * 16 + kc * 4 + r;
                    int j = cc * 16 + m15;
                    int off = nl * 2048 + j * 2;             // bytes
                    *(short*)((char*)s_F + swzF(off)) = f2bf(acc[r]);
                }
            }
        }
    }
    __syncthreads();

    // ---- Phase D (MFMA): out[n][o] = (sum_j F[n][j] * Wt[o][j])/32 + bias[o] ----
    // GEMM M=16(n) N=16(o per wave, otile=wave) K=1024
    {
        const int m15 = lane & 15;
        const int kc = lane >> 4;
        const int o = wave * 16 + m15;
        f32x4 acc0 = {0.f, 0.f, 0.f, 0.f};
        f32x4 acc1 = {0.f, 0.f, 0.f, 0.f};
        const short* wrow = Wt + o * 1024;
        #pragma unroll
        for (int ks = 0; ks < 32; ++ks) {
            const int j0 = kc * 8 + ks * 32;
            int aoff = m15 * 2048 + j0 * 2;                  // bytes; n = m15
            bf16x8 af = *(const bf16x8*)((const char*)s_F + swzF(aoff));
            bf16x8 bf = *(const bf16x8*)(wrow + j0);
            if (ks & 1) acc1 = __builtin_amdgcn_mfma_f32_16x16x32_bf16(af, bf, acc1, 0, 0, 0);
            else        acc0 = __builtin_amdgcn_mfma_f32_16x16x32_bf16(af, bf, acc0, 0, 0, 0);
        }
        const float bo = bias[o];
        float4 ov;
        ov.x = (acc0[0] + acc1[0]) * (1.f / 32.f) + bo;
        ov.y = (acc0[1] + acc1[1]) * (1.f / 32.f) + bo;
        ov.z = (acc0[2] + acc1[2]) * (1.f / 32.f) + bo;
        ov.w = (acc0[3] + acc1[3]) * (1.f / 32.f) + bo;
        // D rows: n = kc*4 + r (4 consecutive) at col o
        *(float4*)&out0[(size_t)(b * OUT_ + o) * NS_ + n0 + kc * 4] = ov;
    }
}

extern "C" void kernel_launch(void* const* d_in, const int* in_sizes, int n_in,
                              void* d_out, int out_size, void* d_ws, size_t ws_size,
                              hipStream_t stream) {
    const float* input   = (const float*)d_in[0];
    const float* points  = (const float*)d_in[1];
    const float* support = (const float*)d_in[2];
    const float* weight  = (const float*)d_in[3];
    const float* bias    = (const float*)d_in[4];
    const float* centers = (const float*)d_in[5];
    const float* W1 = (const float*)d_in[6];
    const float* b1 = (const float*)d_in[7];
    const float* W2 = (const float*)d_in[8];
    const float* b2 = (const float*)d_in[9];
    const float* W3 = (const float*)d_in[10];
    const float* b3 = (const float*)d_in[11];

    float* out0 = (float*)d_out;
    float* out1 = out0 + (size_t)B_ * OUT_ * NS_;

    short* wt  = (short*)d_ws;                       // 128 KB
    float* w1c = (float*)((char*)d_ws + 131072);     // 256 B
    setup_kernel<<<257, 256, 0, stream>>>(weight, wt, W1, b1, centers, w1c);

    dim3 grid(B_ * (NS_ / G_));
    convpoint_kernel<<<grid, 256, 0, stream>>>(
        input, points, support, wt, w1c, bias,
        W2, b2, W3, b3, out0, out1);
}